// Round 4
// baseline (543.722 us; speedup 1.0000x reference)
//
#include <hip/hip_runtime.h>
#include <math.h>

#define N_B 4
#define IMG 192

typedef __attribute__((ext_vector_type(8))) short short8;
typedef __attribute__((ext_vector_type(4))) float f32x4;

__device__ __forceinline__ unsigned f2bf(float f) {
  unsigned u = __float_as_uint(f);
  return (u + 0x7fffu + ((u >> 16) & 1u)) >> 16;   // RNE to bf16 bits
}
__device__ __forceinline__ float bf2f(unsigned b) {
  return __uint_as_float(b << 16);
}

// ---------------- down path ----------------
__global__ void k_d1(const float* __restrict__ x, const float* __restrict__ w,
                     float* __restrict__ out) {
  int idx = blockIdx.x * 256 + threadIdx.x;            // (4,16,48,48)
  if (idx >= N_B * 16 * 48 * 48) return;
  int xq = idx % 48; int t = idx / 48; int yq = t % 48; t /= 48;
  int oc = t % 16; int b = t / 16;
  const float* xp = x + (b * IMG + yq * 4) * IMG + xq * 4;
  const float* wp = w + oc * 16;
  float s = 0.f;
#pragma unroll
  for (int dy = 0; dy < 4; ++dy)
#pragma unroll
    for (int dx = 0; dx < 4; ++dx)
      s = fmaf(xp[dy * IMG + dx], wp[dy * 4 + dx], s);
  out[idx] = fmaxf(s, 0.f);
}

__global__ void k_d2(const float* __restrict__ h1, const float* __restrict__ w,
                     float* __restrict__ out) {
  int idx = blockIdx.x * 256 + threadIdx.x;            // (4,256,12,12)
  if (idx >= N_B * 256 * 12 * 12) return;
  int xq = idx % 12; int t = idx / 12; int yq = t % 12; t /= 12;
  int oc = t % 256; int b = t / 256;
  float s = 0.f;
  for (int ci = 0; ci < 16; ++ci) {
    const float* ip = h1 + ((b * 16 + ci) * 48 + yq * 4) * 48 + xq * 4;
    const float* wp = w + (oc * 16 + ci) * 16;
#pragma unroll
    for (int dy = 0; dy < 4; ++dy)
#pragma unroll
      for (int dx = 0; dx < 4; ++dx)
        s = fmaf(ip[dy * 48 + dx], wp[dy * 4 + dx], s);
  }
  out[idx] = fmaxf(s, 0.f);
}

// d3 writes TRANSPOSED: h3t[(b*36 + p)*1024 + oc]
__global__ void k_d3(const float* __restrict__ h2, const float* __restrict__ w,
                     float* __restrict__ out) {
  int idx = blockIdx.x * 256 + threadIdx.x;            // (4,1024,6,6)
  if (idx >= N_B * 1024 * 36) return;
  int xq = idx % 6; int t = idx / 6; int yq = t % 6; t /= 6;
  int oc = t % 1024; int b = t / 1024;
  float s = 0.f;
  for (int ci = 0; ci < 256; ++ci) {
    const float* ip = h2 + ((b * 256 + ci) * 12 + yq * 2) * 12 + xq * 2;
    const float* wp = w + (oc * 256 + ci) * 4;
    s = fmaf(ip[0], wp[0], s);
    s = fmaf(ip[1], wp[1], s);
    s = fmaf(ip[12], wp[2], s);
    s = fmaf(ip[13], wp[3], s);
  }
  out[(b * 36 + yq * 6 + xq) * 1024 + oc] = fmaxf(s, 0.f);
}

// fused: d4 (1x1) + STE quantize + 3x qcm + up-conv + depth_to_space
// one block per (b, pixel); 144 blocks, 512 threads
__global__ __launch_bounds__(512) void k_mid(
    const float* __restrict__ h3t, const float* __restrict__ d4_w,
    const float* __restrict__ q1_w, const float* __restrict__ q1_b,
    const float* __restrict__ q2_w, const float* __restrict__ q2_b,
    const float* __restrict__ q3_w, const float* __restrict__ q3_b,
    const float* __restrict__ up_w, const float* __restrict__ up_b,
    float* __restrict__ x4_out, float* __restrict__ xcomp_out,
    float* __restrict__ y_out) {
  __shared__ float hv[1024];
  __shared__ float part[512];
  __shared__ float tv[160];
  __shared__ float xrv[160];
  int blk = blockIdx.x;
  int b = blk / 36, p = blk % 36;
  int tid = threadIdx.x;
  for (int i = tid; i < 1024; i += 512) hv[i] = h3t[(size_t)blk * 1024 + i];
  __syncthreads();
  // ---- x4 = d4_w . hv (2-way split dot) ----
  {
    int half = tid >> 8, oc = tid & 255;
    float s = 0.f;
    if (oc < 154) {
      const float* wp = d4_w + (size_t)oc * 1024 + half * 512;
      const float* hp = hv + half * 512;
      float a0 = 0.f, a1 = 0.f, a2 = 0.f, a3 = 0.f;
      for (int i = 0; i < 512; i += 4) {
        a0 = fmaf(hp[i], wp[i], a0);
        a1 = fmaf(hp[i + 1], wp[i + 1], a1);
        a2 = fmaf(hp[i + 2], wp[i + 2], a2);
        a3 = fmaf(hp[i + 3], wp[i + 3], a3);
      }
      s = (a0 + a1) + (a2 + a3);
    }
    part[tid] = s;
  }
  __syncthreads();
  if (tid < 154) {
    float s = part[tid] + part[tid + 256];
    x4_out[(b * 154 + tid) * 36 + p] = s;
    float q = floorf(s / 0.01f) * 0.01f;
    xrv[tid] = q;
    tv[tid] = q;
  }
  __syncthreads();
  // ---- 3x quant-compensation ----
  const float* qw[3] = {q1_w, q2_w, q3_w};
  const float* qb[3] = {q1_b, q2_b, q3_b};
  for (int l = 0; l < 3; ++l) {
    float s = 0.f;
    if (tid < 154) {
      const float* wp = qw[l] + (size_t)tid * 154;
      float a0 = 0.f, a1 = 0.f;
      int i = 0;
      for (; i + 1 < 154; i += 2) {
        a0 = fmaf(tv[i], wp[i], a0);
        a1 = fmaf(tv[i + 1], wp[i + 1], a1);
      }
      if (i < 154) a0 = fmaf(tv[i], wp[i], a0);
      s = qb[l][tid] + a0 + a1;
    }
    __syncthreads();
    if (tid < 154) tv[tid] = fmaxf(s, 0.f) + tv[tid];
    __syncthreads();
  }
  // ---- x_comp = t + xr ----
  if (tid < 154) {
    float xc = tv[tid] + xrv[tid];
    tv[tid] = xc;
    xcomp_out[(b * 154 + tid) * 36 + p] = xc;
  }
  __syncthreads();
  // ---- up conv + depth_to_space (2 outputs per thread) ----
  int h = p / 6, w6 = p % 6;
#pragma unroll
  for (int k = 0; k < 2; ++k) {
    int co = k * 512 + tid;
    const float* wp = up_w + (size_t)co * 154;
    float a0 = 0.f, a1 = 0.f;
    int i = 0;
    for (; i + 1 < 154; i += 2) {
      a0 = fmaf(tv[i], wp[i], a0);
      a1 = fmaf(tv[i + 1], wp[i + 1], a1);
    }
    if (i < 154) a0 = fmaf(tv[i], wp[i], a0);
    float s = up_b[co] + a0 + a1;
    int i32 = co >> 5, j = co & 31;
    y_out[(b * IMG + h * 32 + i32) * IMG + w6 * 32 + j] = s;
  }
}

// c1: 3x3 conv 1->64 + prelu; writes B1 = b1 (bf16 NHWC) and S1 = b1+y (bf16 NHWC)
__global__ __launch_bounds__(256) void k_c1b(const float* __restrict__ y,
                                             const float* __restrict__ w,
                                             const float* __restrict__ bias,
                                             const float* __restrict__ a_p,
                                             short* __restrict__ B1,
                                             short* __restrict__ S1) {
  int idx = blockIdx.x * 256 + threadIdx.x;            // pixels
  if (idx >= N_B * IMG * IMG) return;
  int X = idx % IMG; int t = idx / IMG; int Y = t % IMG; int b = t / IMG;
  float p[9];
#pragma unroll
  for (int dy = 0; dy < 3; ++dy)
#pragma unroll
    for (int dx = 0; dx < 3; ++dx) {
      int gy = Y + dy - 1, gx = X + dx - 1;
      p[dy * 3 + dx] = ((unsigned)gy < (unsigned)IMG && (unsigned)gx < (unsigned)IMG)
                           ? y[(b * IMG + gy) * IMG + gx]
                           : 0.f;
    }
  float a = *a_p;
  float yc = p[4];
  size_t base = (size_t)idx * 64;
  for (int oc = 0; oc < 64; oc += 8) {
    unsigned bw[4], sw[4];
#pragma unroll
    for (int j = 0; j < 8; ++j) {
      float s = bias[oc + j];
      const float* wq = w + (oc + j) * 9;
#pragma unroll
      for (int k = 0; k < 9; ++k) s = fmaf(p[k], wq[k], s);
      s = s >= 0.f ? s : a * s;
      float sv = s + yc;
      if (j & 1) { bw[j >> 1] |= f2bf(s) << 16; sw[j >> 1] |= f2bf(sv) << 16; }
      else       { bw[j >> 1] = f2bf(s);        sw[j >> 1] = f2bf(sv); }
    }
    *(uint4*)(B1 + base + oc) = make_uint4(bw[0], bw[1], bw[2], bw[3]);
    *(uint4*)(S1 + base + oc) = make_uint4(sw[0], sw[1], sw[2], sw[3]);
  }
}

// pack all 4 conv weights fp32 [oc][64][3][3] -> bf16 [tap][oc][64 ic]
__global__ __launch_bounds__(256) void k_wprep4(
    const float* __restrict__ w2, const float* __restrict__ w3,
    const float* __restrict__ w4, const float* __restrict__ w5,
    short* __restrict__ o2, short* __restrict__ o3,
    short* __restrict__ o4, short* __restrict__ o5) {
  int which = blockIdx.y;
  const float* w = (which == 0) ? w2 : (which == 1) ? w3 : (which == 2) ? w4 : w5;
  short* o = (which == 0) ? o2 : (which == 1) ? o3 : (which == 2) ? o4 : o5;
  int OC = (which == 3) ? 256 : 64;
  int idx = blockIdx.x * 256 + threadIdx.x;
  if (idx >= OC * 64 * 9) return;
  int tap = idx % 9; int t = idx / 9; int ic = t % 64; int oc = t / 64;
  o[(tap * OC + oc) * 64 + ic] = (short)f2bf(w[idx]);
}

// ---- MFMA implicit-GEMM 3x3 conv, IC=64, bf16 NHWC input (pre-added resid) ----
// tile: 4 rows x 32 cols, 64 oc per block, 4 waves (1 row per wave).
// MODE 0: write bout=b_n (bf16) and sout=b_n+bprev (bf16), prelu
// MODE 1: write sout only, prelu
// MODE 2: write fout fp32 NCHW, no prelu (operand-swapped MFMA -> dwordx4 stores)
template <int MODE>
__global__ __launch_bounds__(256, 5) void k_conv3x3b(
    const short* __restrict__ sin, const short* __restrict__ bprev,
    const short* __restrict__ wbf, const float* __restrict__ bias,
    const float* __restrict__ a_p, short* __restrict__ bout,
    short* __restrict__ sout, float* __restrict__ fout, int ocg_count) {
  __shared__ __align__(16) char smem[204 * 128];     // 6x34 pixels x 64ch bf16
  int tid = threadIdx.x;
  int g = blockIdx.z % ocg_count, b = blockIdx.z / ocg_count;
  int x0 = blockIdx.x * 32, y0 = blockIdx.y * 4;
  int OCtot = ocg_count * 64;

  // ---- stage: bf16 global -> bf16 LDS, XOR swizzled ----
  for (int idx = tid; idx < 204 * 8; idx += 256) {
    int pix = idx >> 3, icq = idx & 7;
    int py = pix / 34, px = pix % 34;
    int gy = y0 - 1 + py, gx = x0 - 1 + px;
    uint4 v = make_uint4(0u, 0u, 0u, 0u);
    if ((unsigned)gy < (unsigned)IMG && (unsigned)gx < (unsigned)IMG)
      v = *(const uint4*)(sin + (size_t)((b * IMG + gy) * IMG + gx) * 64 + icq * 8);
    int byte = (pix * 128 + icq * 16) ^ ((pix & 7) << 4);
    *(uint4*)(smem + byte) = v;
  }
  __syncthreads();

  int w = tid >> 6, lane = tid & 63, li = lane & 15, lg = lane >> 4;
  f32x4 acc[4][2];
#pragma unroll
  for (int mt = 0; mt < 4; ++mt)
#pragma unroll
    for (int nt = 0; nt < 2; ++nt) acc[mt][nt] = (f32x4){0.f, 0.f, 0.f, 0.f};

  __builtin_amdgcn_s_setprio(1);
#pragma unroll
  for (int tap = 0; tap < 9; ++tap) {
    const int dy = tap / 3, dx = tap % 3;
#pragma unroll
    for (int ks = 0; ks < 2; ++ks) {
      short8 bfr[2];
#pragma unroll
      for (int nt = 0; nt < 2; ++nt) {
        int pix = (w + dy) * 34 + nt * 16 + dx + li;
        int byte = (pix * 128 + ks * 64 + lg * 16) ^ ((pix & 7) << 4);
        bfr[nt] = *(const short8*)(smem + byte);
      }
      short8 afr[4];
#pragma unroll
      for (int mt = 0; mt < 4; ++mt)
        afr[mt] = *(const short8*)(wbf +
            ((size_t)(tap * OCtot + g * 64 + mt * 16 + li) * 64 + ks * 32 + lg * 8));
#pragma unroll
      for (int mt = 0; mt < 4; ++mt)
#pragma unroll
        for (int nt = 0; nt < 2; ++nt)
          acc[mt][nt] = (MODE == 2)
              ? __builtin_amdgcn_mfma_f32_16x16x32_bf16(bfr[nt], afr[mt],
                                                        acc[mt][nt], 0, 0, 0)
              : __builtin_amdgcn_mfma_f32_16x16x32_bf16(afr[mt], bfr[nt],
                                                        acc[mt][nt], 0, 0, 0);
    }
  }
  __builtin_amdgcn_s_setprio(0);

  // ---- epilogue ----
  int gy = y0 + w;
  if (MODE != 2) {
    float a = *a_p;
#pragma unroll
    for (int nt = 0; nt < 2; ++nt) {
      int gx = x0 + nt * 16 + li;
#pragma unroll
      for (int mt = 0; mt < 4; ++mt) {
        int ocl = mt * 16 + lg * 4;
        float4 bv = *(const float4*)(bias + g * 64 + ocl);
        f32x4 v = acc[mt][nt];
        float r0 = v[0] + bv.x, r1 = v[1] + bv.y, r2 = v[2] + bv.z, r3 = v[3] + bv.w;
        r0 = r0 >= 0.f ? r0 : a * r0;
        r1 = r1 >= 0.f ? r1 : a * r1;
        r2 = r2 >= 0.f ? r2 : a * r2;
        r3 = r3 >= 0.f ? r3 : a * r3;
        size_t pi = (size_t)((b * IMG + gy) * IMG + gx) * 64 + ocl;
        if (MODE == 0)
          *(uint2*)(bout + pi) = make_uint2(f2bf(r0) | (f2bf(r1) << 16),
                                            f2bf(r2) | (f2bf(r3) << 16));
        uint2 pv = *(const uint2*)(bprev + pi);
        float s0 = r0 + bf2f(pv.x & 0xffffu);
        float s1 = r1 + bf2f(pv.x >> 16);
        float s2 = r2 + bf2f(pv.y & 0xffffu);
        float s3 = r3 + bf2f(pv.y >> 16);
        *(uint2*)(sout + pi) = make_uint2(f2bf(s0) | (f2bf(s1) << 16),
                                          f2bf(s2) | (f2bf(s3) << 16));
      }
    }
  } else {
    // acc row = pixel (lg*4+reg), col = oc (li): dwordx4 stores along gx
#pragma unroll
    for (int nt = 0; nt < 2; ++nt) {
      int gx = x0 + nt * 16 + lg * 4;
#pragma unroll
      for (int mt = 0; mt < 4; ++mt) {
        int oc = g * 64 + mt * 16 + li;
        float bv = bias[oc];
        f32x4 v = acc[mt][nt];
        *(float4*)(fout + (((size_t)b * OCtot + oc) * IMG + gy) * IMG + gx) =
            make_float4(v[0] + bv, v[1] + bv, v[2] + bv, v[3] + bv);
      }
    }
  }
}

// ---------------------------------------------------------------------------
extern "C" void kernel_launch(void* const* d_in, const int* in_sizes, int n_in,
                              void* d_out, int out_size, void* d_ws, size_t ws_size,
                              hipStream_t stream) {
  const float* x    = (const float*)d_in[0];
  const float* d1_w = (const float*)d_in[2];
  const float* d2_w = (const float*)d_in[3];
  const float* d3_w = (const float*)d_in[4];
  const float* d4_w = (const float*)d_in[5];
  const float* q1_w = (const float*)d_in[6];
  const float* q1_b = (const float*)d_in[7];
  const float* q2_w = (const float*)d_in[8];
  const float* q2_b = (const float*)d_in[9];
  const float* q3_w = (const float*)d_in[10];
  const float* q3_b = (const float*)d_in[11];
  const float* up_w = (const float*)d_in[12];
  const float* up_b = (const float*)d_in[13];
  const float* c1_w = (const float*)d_in[14];
  const float* c1_b = (const float*)d_in[15];
  const float* c1_a = (const float*)d_in[16];
  const float* c2_w = (const float*)d_in[17];
  const float* c2_b = (const float*)d_in[18];
  const float* c2_a = (const float*)d_in[19];
  const float* c3_w = (const float*)d_in[20];
  const float* c3_b = (const float*)d_in[21];
  const float* c3_a = (const float*)d_in[22];
  const float* c4_w = (const float*)d_in[23];
  const float* c4_b = (const float*)d_in[24];
  const float* c4_a = (const float*)d_in[25];
  const float* c5_w = (const float*)d_in[26];
  const float* c5_b = (const float*)d_in[27];

  float* out = (float*)d_out;
  float* ws  = (float*)d_ws;

  const size_t B5  = (size_t)N_B * 256 * IMG * IMG;
  const size_t SML = (size_t)N_B * 154 * 36;
  float* out_b5    = out;
  float* out_xcomp = out + B5;
  float* out_x4    = out + B5 + SML;

  const size_t PIX = (size_t)N_B * IMG * IMG;     // 147,456
  size_t off = 0;
  float* h1   = ws + off; off += (size_t)N_B * 16 * 48 * 48;
  float* h2   = ws + off; off += (size_t)N_B * 256 * 12 * 12;
  float* h3t  = ws + off; off += (size_t)N_B * 36 * 1024;
  float* ybuf = ws + off; off += PIX;
  short* sl0  = (short*)(ws + off); off += PIX * 64 / 2;
  short* sl1  = (short*)(ws + off); off += PIX * 64 / 2;
  short* sl2  = (short*)(ws + off); off += PIX * 64 / 2;
  short* sl3  = (short*)(ws + off); off += PIX * 64 / 2;
  short* wb2  = (short*)(ws + off); off += 9 * 64 * 64 / 2;
  short* wb3  = (short*)(ws + off); off += 9 * 64 * 64 / 2;
  short* wb4  = (short*)(ws + off); off += 9 * 64 * 64 / 2;
  short* wb5  = (short*)(ws + off); off += 9 * 256 * 64 / 2;

  // weight packing (independent, single launch)
  dim3 wg((9 * 256 * 64 + 255) / 256, 4);
  k_wprep4<<<wg, 256, 0, stream>>>(c2_w, c3_w, c4_w, c5_w, wb2, wb3, wb4, wb5);

  // ---- down path ----
  k_d1<<<(N_B * 16 * 48 * 48 + 255) / 256, 256, 0, stream>>>(x, d1_w, h1);
  k_d2<<<(N_B * 256 * 12 * 12 + 255) / 256, 256, 0, stream>>>(h1, d2_w, h2);
  k_d3<<<(N_B * 1024 * 36 + 255) / 256, 256, 0, stream>>>(h2, d3_w, h3t);

  // ---- fused d4 + quantize + qcm x3 + up + depth_to_space ----
  k_mid<<<N_B * 36, 512, 0, stream>>>(h3t, d4_w, q1_w, q1_b, q2_w, q2_b,
                                      q3_w, q3_b, up_w, up_b,
                                      out_x4, out_xcomp, ybuf);

  // ---- refinement CNN ----
  k_c1b<<<(int)((PIX + 255) / 256), 256, 0, stream>>>(ybuf, c1_w, c1_b, c1_a,
                                                      sl1 /*B1*/, sl0 /*S1*/);

  dim3 cg(IMG / 32, IMG / 4, N_B);
  // c2: in S1(sl0), bprev B1(sl1) -> B2(sl2), S2(sl3)
  k_conv3x3b<0><<<cg, 256, 0, stream>>>(sl0, sl1, wb2, c2_b, c2_a, sl2, sl3, nullptr, 1);
  // c3: in S2(sl3), bprev B2(sl2) -> B3(sl1), S3(sl0)
  k_conv3x3b<0><<<cg, 256, 0, stream>>>(sl3, sl2, wb3, c3_b, c3_a, sl1, sl0, nullptr, 1);
  // c4: in S3(sl0), bprev B3(sl1) -> S4(sl3)
  k_conv3x3b<1><<<cg, 256, 0, stream>>>(sl0, sl1, wb4, c4_b, c4_a, nullptr, sl3, nullptr, 1);
  // c5: in S4(sl3) -> d_out fp32 NCHW
  dim3 cg5(IMG / 32, IMG / 4, N_B * 4);
  k_conv3x3b<2><<<cg5, 256, 0, stream>>>(sl3, nullptr, wb5, c5_b, nullptr, nullptr, nullptr, out_b5, 4);
}

// Round 5
// 459.227 us; speedup vs baseline: 1.1840x; 1.1840x over previous
//
#include <hip/hip_runtime.h>
#include <math.h>

#define N_B 4
#define IMG 192

typedef __attribute__((ext_vector_type(8))) short short8;
typedef __attribute__((ext_vector_type(4))) float f32x4;

__device__ __forceinline__ unsigned f2bf(float f) {
  unsigned u = __float_as_uint(f);
  return (u + 0x7fffu + ((u >> 16) & 1u)) >> 16;   // RNE to bf16 bits
}
__device__ __forceinline__ float bf2f(unsigned b) {
  return __uint_as_float(b << 16);
}

// ---------------- down path ----------------
__global__ void k_d1(const float* __restrict__ x, const float* __restrict__ w,
                     float* __restrict__ out) {
  int idx = blockIdx.x * 256 + threadIdx.x;            // (4,16,48,48)
  if (idx >= N_B * 16 * 48 * 48) return;
  int xq = idx % 48; int t = idx / 48; int yq = t % 48; t /= 48;
  int oc = t % 16; int b = t / 16;
  const float* xp = x + (b * IMG + yq * 4) * IMG + xq * 4;
  const float* wp = w + oc * 16;
  float s = 0.f;
#pragma unroll
  for (int dy = 0; dy < 4; ++dy)
#pragma unroll
    for (int dx = 0; dx < 4; ++dx)
      s = fmaf(xp[dy * IMG + dx], wp[dy * 4 + dx], s);
  out[idx] = fmaxf(s, 0.f);
}

__global__ void k_d2(const float* __restrict__ h1, const float* __restrict__ w,
                     float* __restrict__ out) {
  int idx = blockIdx.x * 256 + threadIdx.x;            // (4,256,12,12)
  if (idx >= N_B * 256 * 12 * 12) return;
  int xq = idx % 12; int t = idx / 12; int yq = t % 12; t /= 12;
  int oc = t % 256; int b = t / 256;
  float s = 0.f;
  for (int ci = 0; ci < 16; ++ci) {
    const float* ip = h1 + ((b * 16 + ci) * 48 + yq * 4) * 48 + xq * 4;
    const float* wp = w + (oc * 16 + ci) * 16;
#pragma unroll
    for (int dy = 0; dy < 4; ++dy)
#pragma unroll
      for (int dx = 0; dx < 4; ++dx)
        s = fmaf(ip[dy * 48 + dx], wp[dy * 4 + dx], s);
  }
  out[idx] = fmaxf(s, 0.f);
}

// d3 writes TRANSPOSED: h3t[(b*36 + p)*1024 + oc]
__global__ void k_d3(const float* __restrict__ h2, const float* __restrict__ w,
                     float* __restrict__ out) {
  int idx = blockIdx.x * 256 + threadIdx.x;            // (4,1024,6,6)
  if (idx >= N_B * 1024 * 36) return;
  int xq = idx % 6; int t = idx / 6; int yq = t % 6; t /= 6;
  int oc = t % 1024; int b = t / 1024;
  float s = 0.f;
  for (int ci = 0; ci < 256; ++ci) {
    const float* ip = h2 + ((b * 256 + ci) * 12 + yq * 2) * 12 + xq * 2;
    const float* wp = w + (oc * 256 + ci) * 4;
    s = fmaf(ip[0], wp[0], s);
    s = fmaf(ip[1], wp[1], s);
    s = fmaf(ip[12], wp[2], s);
    s = fmaf(ip[13], wp[3], s);
  }
  out[(b * 36 + yq * 6 + xq) * 1024 + oc] = fmaxf(s, 0.f);
}

// fused: d4 (1x1) + STE quantize + 3x qcm + up-conv + depth_to_space
__global__ __launch_bounds__(512) void k_mid(
    const float* __restrict__ h3t, const float* __restrict__ d4_w,
    const float* __restrict__ q1_w, const float* __restrict__ q1_b,
    const float* __restrict__ q2_w, const float* __restrict__ q2_b,
    const float* __restrict__ q3_w, const float* __restrict__ q3_b,
    const float* __restrict__ up_w, const float* __restrict__ up_b,
    float* __restrict__ x4_out, float* __restrict__ xcomp_out,
    float* __restrict__ y_out) {
  __shared__ float hv[1024];
  __shared__ float part[512];
  __shared__ float tv[160];
  __shared__ float xrv[160];
  int blk = blockIdx.x;
  int b = blk / 36, p = blk % 36;
  int tid = threadIdx.x;
  for (int i = tid; i < 1024; i += 512) hv[i] = h3t[(size_t)blk * 1024 + i];
  __syncthreads();
  {
    int half = tid >> 8, oc = tid & 255;
    float s = 0.f;
    if (oc < 154) {
      const float* wp = d4_w + (size_t)oc * 1024 + half * 512;
      const float* hp = hv + half * 512;
      float a0 = 0.f, a1 = 0.f, a2 = 0.f, a3 = 0.f;
      for (int i = 0; i < 512; i += 4) {
        a0 = fmaf(hp[i], wp[i], a0);
        a1 = fmaf(hp[i + 1], wp[i + 1], a1);
        a2 = fmaf(hp[i + 2], wp[i + 2], a2);
        a3 = fmaf(hp[i + 3], wp[i + 3], a3);
      }
      s = (a0 + a1) + (a2 + a3);
    }
    part[tid] = s;
  }
  __syncthreads();
  if (tid < 154) {
    float s = part[tid] + part[tid + 256];
    x4_out[(b * 154 + tid) * 36 + p] = s;
    float q = floorf(s / 0.01f) * 0.01f;
    xrv[tid] = q;
    tv[tid] = q;
  }
  __syncthreads();
  const float* qw[3] = {q1_w, q2_w, q3_w};
  const float* qb[3] = {q1_b, q2_b, q3_b};
  for (int l = 0; l < 3; ++l) {
    float s = 0.f;
    if (tid < 154) {
      const float* wp = qw[l] + (size_t)tid * 154;
      float a0 = 0.f, a1 = 0.f;
      int i = 0;
      for (; i + 1 < 154; i += 2) {
        a0 = fmaf(tv[i], wp[i], a0);
        a1 = fmaf(tv[i + 1], wp[i + 1], a1);
      }
      if (i < 154) a0 = fmaf(tv[i], wp[i], a0);
      s = qb[l][tid] + a0 + a1;
    }
    __syncthreads();
    if (tid < 154) tv[tid] = fmaxf(s, 0.f) + tv[tid];
    __syncthreads();
  }
  if (tid < 154) {
    float xc = tv[tid] + xrv[tid];
    tv[tid] = xc;
    xcomp_out[(b * 154 + tid) * 36 + p] = xc;
  }
  __syncthreads();
  int h = p / 6, w6 = p % 6;
#pragma unroll
  for (int k = 0; k < 2; ++k) {
    int co = k * 512 + tid;
    const float* wp = up_w + (size_t)co * 154;
    float a0 = 0.f, a1 = 0.f;
    int i = 0;
    for (; i + 1 < 154; i += 2) {
      a0 = fmaf(tv[i], wp[i], a0);
      a1 = fmaf(tv[i + 1], wp[i + 1], a1);
    }
    if (i < 154) a0 = fmaf(tv[i], wp[i], a0);
    float s = up_b[co] + a0 + a1;
    int i32 = co >> 5, j = co & 31;
    y_out[(b * IMG + h * 32 + i32) * IMG + w6 * 32 + j] = s;
  }
}

// c1: 3x3 conv 1->64 + prelu; writes B1 = b1 (bf16 NHWC) and S1 = b1+y (bf16 NHWC)
__global__ __launch_bounds__(256) void k_c1b(const float* __restrict__ y,
                                             const float* __restrict__ w,
                                             const float* __restrict__ bias,
                                             const float* __restrict__ a_p,
                                             short* __restrict__ B1,
                                             short* __restrict__ S1) {
  int idx = blockIdx.x * 256 + threadIdx.x;            // pixels
  if (idx >= N_B * IMG * IMG) return;
  int X = idx % IMG; int t = idx / IMG; int Y = t % IMG; int b = t / IMG;
  float p[9];
#pragma unroll
  for (int dy = 0; dy < 3; ++dy)
#pragma unroll
    for (int dx = 0; dx < 3; ++dx) {
      int gy = Y + dy - 1, gx = X + dx - 1;
      p[dy * 3 + dx] = ((unsigned)gy < (unsigned)IMG && (unsigned)gx < (unsigned)IMG)
                           ? y[(b * IMG + gy) * IMG + gx]
                           : 0.f;
    }
  float a = *a_p;
  float yc = p[4];
  size_t base = (size_t)idx * 64;
  for (int oc = 0; oc < 64; oc += 8) {
    unsigned bw[4], sw[4];
#pragma unroll
    for (int j = 0; j < 8; ++j) {
      float s = bias[oc + j];
      const float* wq = w + (oc + j) * 9;
#pragma unroll
      for (int k = 0; k < 9; ++k) s = fmaf(p[k], wq[k], s);
      s = s >= 0.f ? s : a * s;
      float sv = s + yc;
      if (j & 1) { bw[j >> 1] |= f2bf(s) << 16; sw[j >> 1] |= f2bf(sv) << 16; }
      else       { bw[j >> 1] = f2bf(s);        sw[j >> 1] = f2bf(sv); }
    }
    *(uint4*)(B1 + base + oc) = make_uint4(bw[0], bw[1], bw[2], bw[3]);
    *(uint4*)(S1 + base + oc) = make_uint4(sw[0], sw[1], sw[2], sw[3]);
  }
}

// pack all 4 conv weights fp32 [oc][64][3][3] -> bf16 [tap][oc][64 ic]
__global__ __launch_bounds__(256) void k_wprep4(
    const float* __restrict__ w2, const float* __restrict__ w3,
    const float* __restrict__ w4, const float* __restrict__ w5,
    short* __restrict__ o2, short* __restrict__ o3,
    short* __restrict__ o4, short* __restrict__ o5) {
  int which = blockIdx.y;
  const float* w = (which == 0) ? w2 : (which == 1) ? w3 : (which == 2) ? w4 : w5;
  short* o = (which == 0) ? o2 : (which == 1) ? o3 : (which == 2) ? o4 : o5;
  int OC = (which == 3) ? 256 : 64;
  int idx = blockIdx.x * 256 + threadIdx.x;
  if (idx >= OC * 64 * 9) return;
  int tap = idx % 9; int t = idx / 9; int ic = t % 64; int oc = t / 64;
  o[(tap * OC + oc) * 64 + ic] = (short)f2bf(w[idx]);
}

// ---- MFMA implicit-GEMM 3x3 conv, IC=64, bf16 NHWC input (pre-added resid) ----
// tile: 8 rows x 32 cols, 64 oc per block, 4 waves (2 rows per wave).
// Weight A-frags software-pipelined 1 K-step ahead (register double-buffer).
// MODE 0: write bout=b_n (bf16) and sout=b_n+bprev (bf16), prelu
// MODE 1: write sout only, prelu
// MODE 2: write fout fp32 NCHW, no prelu (operand-swapped MFMA -> dwordx4 stores)
template <int MODE>
__global__ __launch_bounds__(256) void k_conv3x3b(
    const short* __restrict__ sin, const short* __restrict__ bprev,
    const short* __restrict__ wbf, const float* __restrict__ bias,
    const float* __restrict__ a_p, short* __restrict__ bout,
    short* __restrict__ sout, float* __restrict__ fout, int ocg_count) {
  __shared__ __align__(16) char smem[340 * 128];     // 10x34 pixels x 64ch bf16
  int tid = threadIdx.x;
  int g = blockIdx.z % ocg_count, b = blockIdx.z / ocg_count;
  int x0 = blockIdx.x * 32, y0 = blockIdx.y * 8;
  int OCtot = ocg_count * 64;

  // ---- stage: bf16 global -> bf16 LDS, XOR swizzled ----
  for (int idx = tid; idx < 340 * 8; idx += 256) {
    int pix = idx >> 3, icq = idx & 7;
    int py = pix / 34, px = pix % 34;
    int gy = y0 - 1 + py, gx = x0 - 1 + px;
    uint4 v = make_uint4(0u, 0u, 0u, 0u);
    if ((unsigned)gy < (unsigned)IMG && (unsigned)gx < (unsigned)IMG)
      v = *(const uint4*)(sin + (size_t)((b * IMG + gy) * IMG + gx) * 64 + icq * 8);
    int byte = (pix * 128 + icq * 16) ^ ((pix & 7) << 4);
    *(uint4*)(smem + byte) = v;
  }
  __syncthreads();

  int w = tid >> 6, lane = tid & 63, li = lane & 15, lg = lane >> 4;
  int row0 = 2 * w;
  const short* abase = wbf + (size_t)(g * 64 + li) * 64 + lg * 8;
  const int tapstride = OCtot * 64;

  f32x4 acc[4][4];
#pragma unroll
  for (int mt = 0; mt < 4; ++mt)
#pragma unroll
    for (int nt = 0; nt < 4; ++nt) acc[mt][nt] = (f32x4){0.f, 0.f, 0.f, 0.f};

#define LOADA(s, dst)                                                          \
  {                                                                            \
    const short* p_ = abase + (size_t)((s) >> 1) * tapstride + ((s) & 1) * 32; \
    _Pragma("unroll") for (int mt = 0; mt < 4; ++mt)                           \
        dst[mt] = *(const short8*)(p_ + mt * 1024);                            \
  }
#define LOADB(s, dst)                                                          \
  {                                                                            \
    const int tap_ = (s) >> 1, ks_ = (s) & 1;                                  \
    const int dy_ = tap_ / 3, dx_ = tap_ % 3;                                  \
    _Pragma("unroll") for (int nt = 0; nt < 4; ++nt) {                         \
      int pix_ = (row0 + (nt >> 1) + dy_) * 34 + (nt & 1) * 16 + dx_ + li;     \
      int byte_ = (pix_ * 128 + ks_ * 64 + lg * 16) ^ ((pix_ & 7) << 4);       \
      dst[nt] = *(const short8*)(smem + byte_);                                \
    }                                                                          \
  }

  short8 Abuf[2][4];
  short8 Bbuf[4];
  LOADA(0, Abuf[0]);
#pragma unroll
  for (int s = 0; s < 18; ++s) {
    if (s + 1 < 18) LOADA(s + 1, Abuf[(s + 1) & 1]);   // prefetch next weights
    LOADB(s, Bbuf);
    short8* Ac = Abuf[s & 1];
#pragma unroll
    for (int mt = 0; mt < 4; ++mt)
#pragma unroll
      for (int nt = 0; nt < 4; ++nt)
        acc[mt][nt] = (MODE == 2)
            ? __builtin_amdgcn_mfma_f32_16x16x32_bf16(Bbuf[nt], Ac[mt],
                                                      acc[mt][nt], 0, 0, 0)
            : __builtin_amdgcn_mfma_f32_16x16x32_bf16(Ac[mt], Bbuf[nt],
                                                      acc[mt][nt], 0, 0, 0);
  }
#undef LOADA
#undef LOADB

  // ---- epilogue ----
  if (MODE != 2) {
    float a = *a_p;
#pragma unroll
    for (int nt = 0; nt < 4; ++nt) {
      int gy = y0 + row0 + (nt >> 1);
      int gx = x0 + (nt & 1) * 16 + li;
#pragma unroll
      for (int mt = 0; mt < 4; ++mt) {
        int ocl = mt * 16 + lg * 4;
        float4 bv = *(const float4*)(bias + g * 64 + ocl);
        f32x4 v = acc[mt][nt];
        float r0 = v[0] + bv.x, r1 = v[1] + bv.y, r2 = v[2] + bv.z, r3 = v[3] + bv.w;
        r0 = r0 >= 0.f ? r0 : a * r0;
        r1 = r1 >= 0.f ? r1 : a * r1;
        r2 = r2 >= 0.f ? r2 : a * r2;
        r3 = r3 >= 0.f ? r3 : a * r3;
        size_t pi = (size_t)((b * IMG + gy) * IMG + gx) * 64 + ocl;
        if (MODE == 0)
          *(uint2*)(bout + pi) = make_uint2(f2bf(r0) | (f2bf(r1) << 16),
                                            f2bf(r2) | (f2bf(r3) << 16));
        uint2 pv = *(const uint2*)(bprev + pi);
        float s0 = r0 + bf2f(pv.x & 0xffffu);
        float s1 = r1 + bf2f(pv.x >> 16);
        float s2 = r2 + bf2f(pv.y & 0xffffu);
        float s3 = r3 + bf2f(pv.y >> 16);
        *(uint2*)(sout + pi) = make_uint2(f2bf(s0) | (f2bf(s1) << 16),
                                          f2bf(s2) | (f2bf(s3) << 16));
      }
    }
  } else {
    // swapped acc: row = pixel (lg*4+j), col = oc (li) -> dwordx4 along gx
#pragma unroll
    for (int nt = 0; nt < 4; ++nt) {
      int gy = y0 + row0 + (nt >> 1);
      int gx = x0 + (nt & 1) * 16 + lg * 4;
#pragma unroll
      for (int mt = 0; mt < 4; ++mt) {
        int oc = g * 64 + mt * 16 + li;
        float bv = bias[oc];
        f32x4 v = acc[mt][nt];
        *(float4*)(fout + (((size_t)b * OCtot + oc) * IMG + gy) * IMG + gx) =
            make_float4(v[0] + bv, v[1] + bv, v[2] + bv, v[3] + bv);
      }
    }
  }
}

// ---------------------------------------------------------------------------
extern "C" void kernel_launch(void* const* d_in, const int* in_sizes, int n_in,
                              void* d_out, int out_size, void* d_ws, size_t ws_size,
                              hipStream_t stream) {
  const float* x    = (const float*)d_in[0];
  const float* d1_w = (const float*)d_in[2];
  const float* d2_w = (const float*)d_in[3];
  const float* d3_w = (const float*)d_in[4];
  const float* d4_w = (const float*)d_in[5];
  const float* q1_w = (const float*)d_in[6];
  const float* q1_b = (const float*)d_in[7];
  const float* q2_w = (const float*)d_in[8];
  const float* q2_b = (const float*)d_in[9];
  const float* q3_w = (const float*)d_in[10];
  const float* q3_b = (const float*)d_in[11];
  const float* up_w = (const float*)d_in[12];
  const float* up_b = (const float*)d_in[13];
  const float* c1_w = (const float*)d_in[14];
  const float* c1_b = (const float*)d_in[15];
  const float* c1_a = (const float*)d_in[16];
  const float* c2_w = (const float*)d_in[17];
  const float* c2_b = (const float*)d_in[18];
  const float* c2_a = (const float*)d_in[19];
  const float* c3_w = (const float*)d_in[20];
  const float* c3_b = (const float*)d_in[21];
  const float* c3_a = (const float*)d_in[22];
  const float* c4_w = (const float*)d_in[23];
  const float* c4_b = (const float*)d_in[24];
  const float* c4_a = (const float*)d_in[25];
  const float* c5_w = (const float*)d_in[26];
  const float* c5_b = (const float*)d_in[27];

  float* out = (float*)d_out;
  float* ws  = (float*)d_ws;

  const size_t B5  = (size_t)N_B * 256 * IMG * IMG;
  const size_t SML = (size_t)N_B * 154 * 36;
  float* out_b5    = out;
  float* out_xcomp = out + B5;
  float* out_x4    = out + B5 + SML;

  const size_t PIX = (size_t)N_B * IMG * IMG;     // 147,456
  size_t off = 0;
  float* h1   = ws + off; off += (size_t)N_B * 16 * 48 * 48;
  float* h2   = ws + off; off += (size_t)N_B * 256 * 12 * 12;
  float* h3t  = ws + off; off += (size_t)N_B * 36 * 1024;
  float* ybuf = ws + off; off += PIX;
  short* sl0  = (short*)(ws + off); off += PIX * 64 / 2;
  short* sl1  = (short*)(ws + off); off += PIX * 64 / 2;
  short* sl2  = (short*)(ws + off); off += PIX * 64 / 2;
  short* sl3  = (short*)(ws + off); off += PIX * 64 / 2;
  short* wb2  = (short*)(ws + off); off += 9 * 64 * 64 / 2;
  short* wb3  = (short*)(ws + off); off += 9 * 64 * 64 / 2;
  short* wb4  = (short*)(ws + off); off += 9 * 64 * 64 / 2;
  short* wb5  = (short*)(ws + off); off += 9 * 256 * 64 / 2;

  // weight packing (independent, single launch)
  dim3 wg((9 * 256 * 64 + 255) / 256, 4);
  k_wprep4<<<wg, 256, 0, stream>>>(c2_w, c3_w, c4_w, c5_w, wb2, wb3, wb4, wb5);

  // ---- down path ----
  k_d1<<<(N_B * 16 * 48 * 48 + 255) / 256, 256, 0, stream>>>(x, d1_w, h1);
  k_d2<<<(N_B * 256 * 12 * 12 + 255) / 256, 256, 0, stream>>>(h1, d2_w, h2);
  k_d3<<<(N_B * 1024 * 36 + 255) / 256, 256, 0, stream>>>(h2, d3_w, h3t);

  // ---- fused d4 + quantize + qcm x3 + up + depth_to_space ----
  k_mid<<<N_B * 36, 512, 0, stream>>>(h3t, d4_w, q1_w, q1_b, q2_w, q2_b,
                                      q3_w, q3_b, up_w, up_b,
                                      out_x4, out_xcomp, ybuf);

  // ---- refinement CNN ----
  k_c1b<<<(int)((PIX + 255) / 256), 256, 0, stream>>>(ybuf, c1_w, c1_b, c1_a,
                                                      sl1 /*B1*/, sl0 /*S1*/);

  dim3 cg(IMG / 32, IMG / 8, N_B);
  // c2: in S1(sl0), bprev B1(sl1) -> B2(sl2), S2(sl3)
  k_conv3x3b<0><<<cg, 256, 0, stream>>>(sl0, sl1, wb2, c2_b, c2_a, sl2, sl3, nullptr, 1);
  // c3: in S2(sl3), bprev B2(sl2) -> B3(sl1), S3(sl0)
  k_conv3x3b<0><<<cg, 256, 0, stream>>>(sl3, sl2, wb3, c3_b, c3_a, sl1, sl0, nullptr, 1);
  // c4: in S3(sl0), bprev B3(sl1) -> S4(sl3)
  k_conv3x3b<1><<<cg, 256, 0, stream>>>(sl0, sl1, wb4, c4_b, c4_a, nullptr, sl3, nullptr, 1);
  // c5: in S4(sl3) -> d_out fp32 NCHW
  dim3 cg5(IMG / 32, IMG / 8, N_B * 4);
  k_conv3x3b<2><<<cg5, 256, 0, stream>>>(sl3, nullptr, wb5, c5_b, nullptr, nullptr, nullptr, out_b5, 4);
}

// Round 7
// 455.826 us; speedup vs baseline: 1.1928x; 1.0075x over previous
//
#include <hip/hip_runtime.h>
#include <math.h>

#define N_B 4
#define IMG 192

typedef __attribute__((ext_vector_type(8))) short short8;
typedef __attribute__((ext_vector_type(4))) float f32x4;

__device__ __forceinline__ unsigned f2bf(float f) {
  unsigned u = __float_as_uint(f);
  return (u + 0x7fffu + ((u >> 16) & 1u)) >> 16;   // RNE to bf16 bits
}
__device__ __forceinline__ float bf2f(unsigned b) {
  return __uint_as_float(b << 16);
}
// universal LDS swizzle for 128B pixel rows
__device__ __forceinline__ int swz(int pix) {
  return ((((pix >> 3) & 3) ^ (pix & 7)) << 4);
}

// ---------------- down path ----------------
__global__ void k_d1(const float* __restrict__ x, const float* __restrict__ w,
                     float* __restrict__ out) {
  int idx = blockIdx.x * 256 + threadIdx.x;            // (4,16,48,48)
  if (idx >= N_B * 16 * 48 * 48) return;
  int xq = idx % 48; int t = idx / 48; int yq = t % 48; t /= 48;
  int oc = t % 16; int b = t / 16;
  const float* xp = x + (b * IMG + yq * 4) * IMG + xq * 4;
  const float* wp = w + oc * 16;
  float s = 0.f;
#pragma unroll
  for (int dy = 0; dy < 4; ++dy)
#pragma unroll
    for (int dx = 0; dx < 4; ++dx)
      s = fmaf(xp[dy * IMG + dx], wp[dy * 4 + dx], s);
  out[idx] = fmaxf(s, 0.f);
}

__global__ void k_d2(const float* __restrict__ h1, const float* __restrict__ w,
                     float* __restrict__ out) {
  int idx = blockIdx.x * 256 + threadIdx.x;            // (4,256,12,12)
  if (idx >= N_B * 256 * 12 * 12) return;
  int xq = idx % 12; int t = idx / 12; int yq = t % 12; t /= 12;
  int oc = t % 256; int b = t / 256;
  float s = 0.f;
  for (int ci = 0; ci < 16; ++ci) {
    const float* ip = h1 + ((b * 16 + ci) * 48 + yq * 4) * 48 + xq * 4;
    const float* wp = w + (oc * 16 + ci) * 16;
#pragma unroll
    for (int dy = 0; dy < 4; ++dy)
#pragma unroll
      for (int dx = 0; dx < 4; ++dx)
        s = fmaf(ip[dy * 48 + dx], wp[dy * 4 + dx], s);
  }
  out[idx] = fmaxf(s, 0.f);
}

// d3 writes TRANSPOSED: h3t[(b*36 + p)*1024 + oc]
__global__ void k_d3(const float* __restrict__ h2, const float* __restrict__ w,
                     float* __restrict__ out) {
  int idx = blockIdx.x * 256 + threadIdx.x;            // (4,1024,6,6)
  if (idx >= N_B * 1024 * 36) return;
  int xq = idx % 6; int t = idx / 6; int yq = t % 6; t /= 6;
  int oc = t % 1024; int b = t / 1024;
  float s = 0.f;
  for (int ci = 0; ci < 256; ++ci) {
    const float* ip = h2 + ((b * 256 + ci) * 12 + yq * 2) * 12 + xq * 2;
    const float* wp = w + (oc * 256 + ci) * 4;
    s = fmaf(ip[0], wp[0], s);
    s = fmaf(ip[1], wp[1], s);
    s = fmaf(ip[12], wp[2], s);
    s = fmaf(ip[13], wp[3], s);
  }
  out[(b * 36 + yq * 6 + xq) * 1024 + oc] = fmaxf(s, 0.f);
}

// fused: d4 (1x1) + STE quantize + 3x qcm + up-conv + depth_to_space
__global__ __launch_bounds__(512) void k_mid(
    const float* __restrict__ h3t, const float* __restrict__ d4_w,
    const float* __restrict__ q1_w, const float* __restrict__ q1_b,
    const float* __restrict__ q2_w, const float* __restrict__ q2_b,
    const float* __restrict__ q3_w, const float* __restrict__ q3_b,
    const float* __restrict__ up_w, const float* __restrict__ up_b,
    float* __restrict__ x4_out, float* __restrict__ xcomp_out,
    float* __restrict__ y_out) {
  __shared__ float hv[1024];
  __shared__ float part[512];
  __shared__ float tv[160];
  __shared__ float xrv[160];
  int blk = blockIdx.x;
  int b = blk / 36, p = blk % 36;
  int tid = threadIdx.x;
  for (int i = tid; i < 1024; i += 512) hv[i] = h3t[(size_t)blk * 1024 + i];
  __syncthreads();
  {
    int half = tid >> 8, oc = tid & 255;
    float s = 0.f;
    if (oc < 154) {
      const float* wp = d4_w + (size_t)oc * 1024 + half * 512;
      const float* hp = hv + half * 512;
      float a0 = 0.f, a1 = 0.f, a2 = 0.f, a3 = 0.f;
      for (int i = 0; i < 512; i += 4) {
        a0 = fmaf(hp[i], wp[i], a0);
        a1 = fmaf(hp[i + 1], wp[i + 1], a1);
        a2 = fmaf(hp[i + 2], wp[i + 2], a2);
        a3 = fmaf(hp[i + 3], wp[i + 3], a3);
      }
      s = (a0 + a1) + (a2 + a3);
    }
    part[tid] = s;
  }
  __syncthreads();
  if (tid < 154) {
    float s = part[tid] + part[tid + 256];
    x4_out[(b * 154 + tid) * 36 + p] = s;
    float q = floorf(s / 0.01f) * 0.01f;
    xrv[tid] = q;
    tv[tid] = q;
  }
  __syncthreads();
  const float* qw[3] = {q1_w, q2_w, q3_w};
  const float* qb[3] = {q1_b, q2_b, q3_b};
  for (int l = 0; l < 3; ++l) {
    float s = 0.f;
    if (tid < 154) {
      const float* wp = qw[l] + (size_t)tid * 154;
      float a0 = 0.f, a1 = 0.f;
      int i = 0;
      for (; i + 1 < 154; i += 2) {
        a0 = fmaf(tv[i], wp[i], a0);
        a1 = fmaf(tv[i + 1], wp[i + 1], a1);
      }
      if (i < 154) a0 = fmaf(tv[i], wp[i], a0);
      s = qb[l][tid] + a0 + a1;
    }
    __syncthreads();
    if (tid < 154) tv[tid] = fmaxf(s, 0.f) + tv[tid];
    __syncthreads();
  }
  if (tid < 154) {
    float xc = tv[tid] + xrv[tid];
    tv[tid] = xc;
    xcomp_out[(b * 154 + tid) * 36 + p] = xc;
  }
  __syncthreads();
  int h = p / 6, w6 = p % 6;
#pragma unroll
  for (int k = 0; k < 2; ++k) {
    int co = k * 512 + tid;
    const float* wp = up_w + (size_t)co * 154;
    float a0 = 0.f, a1 = 0.f;
    int i = 0;
    for (; i + 1 < 154; i += 2) {
      a0 = fmaf(tv[i], wp[i], a0);
      a1 = fmaf(tv[i + 1], wp[i + 1], a1);
    }
    if (i < 154) a0 = fmaf(tv[i], wp[i], a0);
    float s = up_b[co] + a0 + a1;
    int i32 = co >> 5, j = co & 31;
    y_out[(b * IMG + h * 32 + i32) * IMG + w6 * 32 + j] = s;
  }
}

// c1: 3x3 conv 1->64 + prelu; writes B1 = b1 (bf16 NHWC) and S1 = b1+y (bf16 NHWC)
__global__ __launch_bounds__(256) void k_c1b(const float* __restrict__ y,
                                             const float* __restrict__ w,
                                             const float* __restrict__ bias,
                                             const float* __restrict__ a_p,
                                             short* __restrict__ B1,
                                             short* __restrict__ S1) {
  int idx = blockIdx.x * 256 + threadIdx.x;            // pixels
  if (idx >= N_B * IMG * IMG) return;
  int X = idx % IMG; int t = idx / IMG; int Y = t % IMG; int b = t / IMG;
  float p[9];
#pragma unroll
  for (int dy = 0; dy < 3; ++dy)
#pragma unroll
    for (int dx = 0; dx < 3; ++dx) {
      int gy = Y + dy - 1, gx = X + dx - 1;
      p[dy * 3 + dx] = ((unsigned)gy < (unsigned)IMG && (unsigned)gx < (unsigned)IMG)
                           ? y[(b * IMG + gy) * IMG + gx]
                           : 0.f;
    }
  float a = *a_p;
  float yc = p[4];
  size_t base = (size_t)idx * 64;
  for (int oc = 0; oc < 64; oc += 8) {
    unsigned bw[4], sw[4];
#pragma unroll
    for (int j = 0; j < 8; ++j) {
      float s = bias[oc + j];
      const float* wq = w + (oc + j) * 9;
#pragma unroll
      for (int k = 0; k < 9; ++k) s = fmaf(p[k], wq[k], s);
      s = s >= 0.f ? s : a * s;
      float sv = s + yc;
      if (j & 1) { bw[j >> 1] |= f2bf(s) << 16; sw[j >> 1] |= f2bf(sv) << 16; }
      else       { bw[j >> 1] = f2bf(s);        sw[j >> 1] = f2bf(sv); }
    }
    *(uint4*)(B1 + base + oc) = make_uint4(bw[0], bw[1], bw[2], bw[3]);
    *(uint4*)(S1 + base + oc) = make_uint4(sw[0], sw[1], sw[2], sw[3]);
  }
}

// pack conv weights fp32 [oc][64][3][3] -> bf16 [tap][row][64 ic].
// For layers c2-c4 (which<3): row r holds LOGICAL oc = ((r>>2)&3)*16 + (r>>4)*4 + (r&3)
// so each lane's epilogue values are 16 consecutive oc. c5 (which==3): identity.
__global__ __launch_bounds__(256) void k_wprep4(
    const float* __restrict__ w2, const float* __restrict__ w3,
    const float* __restrict__ w4, const float* __restrict__ w5,
    short* __restrict__ o2, short* __restrict__ o3,
    short* __restrict__ o4, short* __restrict__ o5) {
  int which = blockIdx.y;
  const float* w = (which == 0) ? w2 : (which == 1) ? w3 : (which == 2) ? w4 : w5;
  short* o = (which == 0) ? o2 : (which == 1) ? o3 : (which == 2) ? o4 : o5;
  int OC = (which == 3) ? 256 : 64;
  int idx = blockIdx.x * 256 + threadIdx.x;
  if (idx >= OC * 64 * 9) return;
  int ic = idx & 63; int t = idx >> 6; int r = t % OC; int tap = t / OC;
  int oc = (which < 3) ? (((r >> 2) & 3) * 16 + ((r >> 4) & 3) * 4 + (r & 3)) : r;
  o[(tap * OC + r) * 64 + ic] = (short)f2bf(w[((size_t)oc * 64 + ic) * 9 + tap]);
}

// ---- MFMA implicit-GEMM 3x3 conv, IC=64, bf16 NHWC input (pre-added resid) ----
// tile: 8 rows x 32 cols, 64 oc per block, 4 waves (2 rows per wave).
// Weight A-frags software-pipelined 1 K-step ahead (register double-buffer).
// MODE 0: write bout=b_n (bf16) and sout=b_n+bprev (bf16), prelu; dense 32B/lane
// MODE 1: write sout only, prelu; dense
// MODE 2: fout fp32 NCHW via operand swap + pixel-permuted fragments -> 32B/lane NT stores
template <int MODE>
__global__ __launch_bounds__(256) void k_conv3x3b(
    const short* __restrict__ sin, const short* __restrict__ bprev,
    const short* __restrict__ wbf, const float* __restrict__ bias,
    const float* __restrict__ a_p, short* __restrict__ bout,
    short* __restrict__ sout, float* __restrict__ fout, int ocg_count) {
  __shared__ __align__(16) char smem[340 * 128];     // 10x34 pixels x 64ch bf16
  int tid = threadIdx.x;
  int g = blockIdx.z % ocg_count, b = blockIdx.z / ocg_count;
  int x0 = blockIdx.x * 32, y0 = blockIdx.y * 8;
  int OCtot = ocg_count * 64;

  // ---- stage: bf16 global -> bf16 LDS, XOR swizzled ----
  for (int idx = tid; idx < 340 * 8; idx += 256) {
    int pix = idx >> 3, icq = idx & 7;
    int py = pix / 34, px = pix % 34;
    int gy = y0 - 1 + py, gx = x0 - 1 + px;
    uint4 v = make_uint4(0u, 0u, 0u, 0u);
    if ((unsigned)gy < (unsigned)IMG && (unsigned)gx < (unsigned)IMG)
      v = *(const uint4*)(sin + (size_t)((b * IMG + gy) * IMG + gx) * 64 + icq * 8);
    int byte = (pix * 128 + icq * 16) ^ swz(pix);
    *(uint4*)(smem + byte) = v;
  }
  __syncthreads();

  int w = tid >> 6, lane = tid & 63, li = lane & 15, lg = lane >> 4;
  int row0 = 2 * w;
  const short* abase = wbf + (size_t)(g * 64 + li) * 64 + lg * 8;
  const int tapstride = OCtot * 64;

  f32x4 acc[4][4];
#pragma unroll
  for (int mt = 0; mt < 4; ++mt)
#pragma unroll
    for (int nt = 0; nt < 4; ++nt) acc[mt][nt] = (f32x4){0.f, 0.f, 0.f, 0.f};

  // x-offset within tile for B-frag: dense for MODE0/1, permuted for MODE2
  const int xoff = (MODE == 2) ? ((li >> 2) * 8 + (li & 3)) : li;

#define LOADA(s, dst)                                                          \
  {                                                                            \
    const short* p_ = abase + (size_t)((s) >> 1) * tapstride + ((s) & 1) * 32; \
    _Pragma("unroll") for (int mt = 0; mt < 4; ++mt)                           \
        dst[mt] = *(const short8*)(p_ + mt * 1024);                            \
  }
#define LOADB(s, dst)                                                          \
  {                                                                            \
    const int tap_ = (s) >> 1, ks_ = (s) & 1;                                  \
    const int dy_ = tap_ / 3, dx_ = tap_ % 3;                                  \
    _Pragma("unroll") for (int nt = 0; nt < 4; ++nt) {                         \
      int xl_ = (MODE == 2) ? (xoff + ((nt & 1) << 2)) : ((nt & 1) * 16 + xoff); \
      int pix_ = (row0 + (nt >> 1) + dy_) * 34 + xl_ + dx_;                    \
      int byte_ = (pix_ * 128 + ks_ * 64 + lg * 16) ^ swz(pix_);               \
      dst[nt] = *(const short8*)(smem + byte_);                                \
    }                                                                          \
  }

  short8 Abuf[2][4];
  short8 Bbuf[4];
  LOADA(0, Abuf[0]);
#pragma unroll
  for (int s = 0; s < 18; ++s) {
    if (s + 1 < 18) LOADA(s + 1, Abuf[(s + 1) & 1]);   // prefetch next weights
    LOADB(s, Bbuf);
    short8* Ac = Abuf[s & 1];
#pragma unroll
    for (int mt = 0; mt < 4; ++mt)
#pragma unroll
      for (int nt = 0; nt < 4; ++nt)
        acc[mt][nt] = (MODE == 2)
            ? __builtin_amdgcn_mfma_f32_16x16x32_bf16(Bbuf[nt], Ac[mt],
                                                      acc[mt][nt], 0, 0, 0)
            : __builtin_amdgcn_mfma_f32_16x16x32_bf16(Ac[mt], Bbuf[nt],
                                                      acc[mt][nt], 0, 0, 0);
  }
#undef LOADA
#undef LOADB

  // ---- epilogue ----
  if (MODE != 2) {
    // lane holds logical oc = lg*16 + mt*4 + j (weight rows permuted at pack)
    float a = *a_p;
#pragma unroll
    for (int nt = 0; nt < 4; ++nt) {
      int gy = y0 + row0 + (nt >> 1);
      int gx = x0 + (nt & 1) * 16 + li;
      float r[16];
#pragma unroll
      for (int mt = 0; mt < 4; ++mt) {
        float4 bv = *(const float4*)(bias + g * 64 + lg * 16 + mt * 4);
        f32x4 v = acc[mt][nt];
        float t0 = v[0] + bv.x, t1 = v[1] + bv.y, t2 = v[2] + bv.z, t3 = v[3] + bv.w;
        r[mt * 4 + 0] = t0 >= 0.f ? t0 : a * t0;
        r[mt * 4 + 1] = t1 >= 0.f ? t1 : a * t1;
        r[mt * 4 + 2] = t2 >= 0.f ? t2 : a * t2;
        r[mt * 4 + 3] = t3 >= 0.f ? t3 : a * t3;
      }
      size_t pi = (size_t)((b * IMG + gy) * IMG + gx) * 64 + lg * 16;  // shorts
      if (MODE == 0) {
        uint4 u0 = make_uint4(f2bf(r[0]) | (f2bf(r[1]) << 16),
                              f2bf(r[2]) | (f2bf(r[3]) << 16),
                              f2bf(r[4]) | (f2bf(r[5]) << 16),
                              f2bf(r[6]) | (f2bf(r[7]) << 16));
        uint4 u1 = make_uint4(f2bf(r[8]) | (f2bf(r[9]) << 16),
                              f2bf(r[10]) | (f2bf(r[11]) << 16),
                              f2bf(r[12]) | (f2bf(r[13]) << 16),
                              f2bf(r[14]) | (f2bf(r[15]) << 16));
        *(uint4*)(bout + pi) = u0;
        *(uint4*)(bout + pi + 8) = u1;
      }
      uint4 p0 = *(const uint4*)(bprev + pi);
      uint4 p1 = *(const uint4*)(bprev + pi + 8);
      unsigned pw[8] = {p0.x, p0.y, p0.z, p0.w, p1.x, p1.y, p1.z, p1.w};
      unsigned so[8];
#pragma unroll
      for (int k = 0; k < 8; ++k) {
        float s0 = r[2 * k] + bf2f(pw[k] & 0xffffu);
        float s1 = r[2 * k + 1] + bf2f(pw[k] >> 16);
        so[k] = f2bf(s0) | (f2bf(s1) << 16);
      }
      *(uint4*)(sout + pi) = make_uint4(so[0], so[1], so[2], so[3]);
      *(uint4*)(sout + pi + 8) = make_uint4(so[4], so[5], so[6], so[7]);
    }
  } else {
    // swapped+permuted acc: lane holds gx = x0 + lg*8 + {0..7} for oc = g*64+mt*16+li
#pragma unroll
    for (int r2 = 0; r2 < 2; ++r2) {
      int gy = y0 + row0 + r2;
      int gxb = x0 + lg * 8;
#pragma unroll
      for (int mt = 0; mt < 4; ++mt) {
        int oc = g * 64 + mt * 16 + li;
        float bv = bias[oc];
        f32x4 v0 = acc[mt][r2 * 2 + 0];
        f32x4 v1 = acc[mt][r2 * 2 + 1];
        float* dst = fout + (((size_t)b * OCtot + oc) * IMG + gy) * IMG + gxb;
        f32x4 s0 = {v0[0] + bv, v0[1] + bv, v0[2] + bv, v0[3] + bv};
        f32x4 s1 = {v1[0] + bv, v1[1] + bv, v1[2] + bv, v1[3] + bv};
        __builtin_nontemporal_store(s0, (f32x4*)dst);
        __builtin_nontemporal_store(s1, (f32x4*)(dst + 4));
      }
    }
  }
}

// ---------------------------------------------------------------------------
extern "C" void kernel_launch(void* const* d_in, const int* in_sizes, int n_in,
                              void* d_out, int out_size, void* d_ws, size_t ws_size,
                              hipStream_t stream) {
  const float* x    = (const float*)d_in[0];
  const float* d1_w = (const float*)d_in[2];
  const float* d2_w = (const float*)d_in[3];
  const float* d3_w = (const float*)d_in[4];
  const float* d4_w = (const float*)d_in[5];
  const float* q1_w = (const float*)d_in[6];
  const float* q1_b = (const float*)d_in[7];
  const float* q2_w = (const float*)d_in[8];
  const float* q2_b = (const float*)d_in[9];
  const float* q3_w = (const float*)d_in[10];
  const float* q3_b = (const float*)d_in[11];
  const float* up_w = (const float*)d_in[12];
  const float* up_b = (const float*)d_in[13];
  const float* c1_w = (const float*)d_in[14];
  const float* c1_b = (const float*)d_in[15];
  const float* c1_a = (const float*)d_in[16];
  const float* c2_w = (const float*)d_in[17];
  const float* c2_b = (const float*)d_in[18];
  const float* c2_a = (const float*)d_in[19];
  const float* c3_w = (const float*)d_in[20];
  const float* c3_b = (const float*)d_in[21];
  const float* c3_a = (const float*)d_in[22];
  const float* c4_w = (const float*)d_in[23];
  const float* c4_b = (const float*)d_in[24];
  const float* c4_a = (const float*)d_in[25];
  const float* c5_w = (const float*)d_in[26];
  const float* c5_b = (const float*)d_in[27];

  float* out = (float*)d_out;
  float* ws  = (float*)d_ws;

  const size_t B5  = (size_t)N_B * 256 * IMG * IMG;
  const size_t SML = (size_t)N_B * 154 * 36;
  float* out_b5    = out;
  float* out_xcomp = out + B5;
  float* out_x4    = out + B5 + SML;

  const size_t PIX = (size_t)N_B * IMG * IMG;     // 147,456
  size_t off = 0;
  float* h1   = ws + off; off += (size_t)N_B * 16 * 48 * 48;
  float* h2   = ws + off; off += (size_t)N_B * 256 * 12 * 12;
  float* h3t  = ws + off; off += (size_t)N_B * 36 * 1024;
  float* ybuf = ws + off; off += PIX;
  short* sl0  = (short*)(ws + off); off += PIX * 64 / 2;
  short* sl1  = (short*)(ws + off); off += PIX * 64 / 2;
  short* sl2  = (short*)(ws + off); off += PIX * 64 / 2;
  short* sl3  = (short*)(ws + off); off += PIX * 64 / 2;
  short* wb2  = (short*)(ws + off); off += 9 * 64 * 64 / 2;
  short* wb3  = (short*)(ws + off); off += 9 * 64 * 64 / 2;
  short* wb4  = (short*)(ws + off); off += 9 * 64 * 64 / 2;
  short* wb5  = (short*)(ws + off); off += 9 * 256 * 64 / 2;

  // weight packing (independent, single launch; permuted rows for c2-c4)
  dim3 wg((9 * 256 * 64 + 255) / 256, 4);
  k_wprep4<<<wg, 256, 0, stream>>>(c2_w, c3_w, c4_w, c5_w, wb2, wb3, wb4, wb5);

  // ---- down path ----
  k_d1<<<(N_B * 16 * 48 * 48 + 255) / 256, 256, 0, stream>>>(x, d1_w, h1);
  k_d2<<<(N_B * 256 * 12 * 12 + 255) / 256, 256, 0, stream>>>(h1, d2_w, h2);
  k_d3<<<(N_B * 1024 * 36 + 255) / 256, 256, 0, stream>>>(h2, d3_w, h3t);

  // ---- fused d4 + quantize + qcm x3 + up + depth_to_space ----
  k_mid<<<N_B * 36, 512, 0, stream>>>(h3t, d4_w, q1_w, q1_b, q2_w, q2_b,
                                      q3_w, q3_b, up_w, up_b,
                                      out_x4, out_xcomp, ybuf);

  // ---- refinement CNN ----
  k_c1b<<<(int)((PIX + 255) / 256), 256, 0, stream>>>(ybuf, c1_w, c1_b, c1_a,
                                                      sl1 /*B1*/, sl0 /*S1*/);

  dim3 cg(IMG / 32, IMG / 8, N_B);
  // c2: in S1(sl0), bprev B1(sl1) -> B2(sl2), S2(sl3)
  k_conv3x3b<0><<<cg, 256, 0, stream>>>(sl0, sl1, wb2, c2_b, c2_a, sl2, sl3, nullptr, 1);
  // c3: in S2(sl3), bprev B2(sl2) -> B3(sl1), S3(sl0)
  k_conv3x3b<0><<<cg, 256, 0, stream>>>(sl3, sl2, wb3, c3_b, c3_a, sl1, sl0, nullptr, 1);
  // c4: in S3(sl0), bprev B3(sl1) -> S4(sl3)
  k_conv3x3b<1><<<cg, 256, 0, stream>>>(sl0, sl1, wb4, c4_b, c4_a, nullptr, sl3, nullptr, 1);
  // c5: in S4(sl3) -> d_out fp32 NCHW
  dim3 cg5(IMG / 32, IMG / 8, N_B * 4);
  k_conv3x3b<2><<<cg5, 256, 0, stream>>>(sl3, nullptr, wb5, c5_b, nullptr, nullptr, nullptr, out_b5, 4);
}